// Round 1
// baseline (6381.453 us; speedup 1.0000x reference)
//
#include <hip/hip_runtime.h>

// Problem constants
#define Sx 256
#define Bx 32
#define Hx 512
#define Gx 2048   // 4H
#define Lx 20
#define Rx 8192   // S*B

typedef __attribute__((ext_vector_type(8))) short short8;
typedef __attribute__((ext_vector_type(4))) float f32x4;

__device__ __forceinline__ unsigned short f2bf(float f) {
  union { float f; unsigned u; } v; v.f = f;
  unsigned u = v.u;
  return (unsigned short)((u + 0x7fffu + ((u >> 16) & 1u)) >> 16);
}
__device__ __forceinline__ float bf2f(unsigned short h) {
  union { unsigned u; float f; } v; v.u = ((unsigned)h) << 16;
  return v.f;
}
__device__ __forceinline__ float sigmf(float x) { return 1.0f / (1.0f + expf(-x)); }

// ---------------- pack / cast kernels ----------------

// x: [B,S,H] fp32 -> xbf: [S,B,H] bf16 (transpose + cast)
__global__ void k_pack_x(const float* __restrict__ x, unsigned short* __restrict__ xbf) {
  int tid = blockIdx.x * 256 + threadIdx.x;      // 0 .. S*B*H-1
  int h = tid & (Hx - 1);
  int r = tid >> 9;          // t*32+b
  int b = r & 31;
  int t = r >> 5;
  xbf[tid] = f2bf(x[(b * Sx + t) * Hx + h]);
}

__global__ void k_cast(const float* __restrict__ s, unsigned short* __restrict__ d, int n) {
  int i = blockIdx.x * 256 + threadIdx.x;
  if (i < n) d[i] = f2bf(s[i]);
}

__global__ void k_add2(const float* __restrict__ a, const float* __restrict__ b,
                       float* __restrict__ o, int n) {
  int i = blockIdx.x * 256 + threadIdx.x;
  if (i < n) o[i] = a[i] + b[i];
}

// ---------------- GEMM: C[M,N](bf16) = A[M,K](bf16) * Bw[N,K]^T(bf16) + bias[N] ----------------
// 128x128 tile, BK=64, 256 threads (2x2 waves of 64x64), 16x16x32 bf16 MFMA.
__global__ __launch_bounds__(256) void k_gemm(
    const unsigned short* __restrict__ A,
    const unsigned short* __restrict__ Bw,
    const float* __restrict__ bias,
    unsigned short* __restrict__ C,
    int M, int N, int K)
{
  const int bn = blockIdx.x, bm = blockIdx.y;
  const int tid = threadIdx.x;
  const int w = tid >> 6, lane = tid & 63;
  const int wr = w >> 1, wc = w & 1;
  const int lo = lane & 15, qd = lane >> 4;

  __shared__ unsigned short As[128 * 72];   // pad 64->72 (2-way LDS conflicts only)
  __shared__ unsigned short Bs[128 * 72];

  f32x4 acc[4][4] = {};

  const int ktn = K >> 6;
  for (int kt = 0; kt < ktn; ++kt) {
    __syncthreads();
    // stage 128x64 of A and Bw
#pragma unroll
    for (int p = 0; p < 4; ++p) {
      int c = tid + (p << 8);          // 0..1023
      int row = c >> 3, kc = c & 7;
      *(short8*)&As[row * 72 + kc * 8] =
          *(const short8*)&A[(size_t)(bm * 128 + row) * K + kt * 64 + kc * 8];
      *(short8*)&Bs[row * 72 + kc * 8] =
          *(const short8*)&Bw[(size_t)(bn * 128 + row) * K + kt * 64 + kc * 8];
    }
    __syncthreads();
#pragma unroll
    for (int kk = 0; kk < 2; ++kk) {
      short8 af[4], bfr[4];
#pragma unroll
      for (int mi = 0; mi < 4; ++mi)
        af[mi] = *(const short8*)&As[(wr * 64 + mi * 16 + lo) * 72 + kk * 32 + qd * 8];
#pragma unroll
      for (int ni = 0; ni < 4; ++ni)
        bfr[ni] = *(const short8*)&Bs[(wc * 64 + ni * 16 + lo) * 72 + kk * 32 + qd * 8];
#pragma unroll
      for (int mi = 0; mi < 4; ++mi)
#pragma unroll
        for (int ni = 0; ni < 4; ++ni)
          acc[mi][ni] = __builtin_amdgcn_mfma_f32_16x16x32_bf16(af[mi], bfr[ni], acc[mi][ni], 0, 0, 0);
    }
  }
  // epilogue: C mapping col=lane&15, row=qd*4+r
#pragma unroll
  for (int mi = 0; mi < 4; ++mi) {
#pragma unroll
    for (int ni = 0; ni < 4; ++ni) {
      int n = bn * 128 + wc * 64 + ni * 16 + lo;
      float bv = bias[n];
#pragma unroll
      for (int r = 0; r < 4; ++r) {
        int m = bm * 128 + wr * 64 + mi * 16 + qd * 4 + r;
        C[(size_t)m * N + n] = f2bf(acc[mi][ni][r] + bv);
      }
    }
  }
}

// ---------------- persistent bidirectional LSTM recurrence ----------------
// grid = 64 WGs x 128 threads. WG wg: dir = wg>>5, slice ws = wg&31 owns h-elems
// j in [ws*16, ws*16+16). Gate rows: {c*512 + j0 + 0..15 : c=0..3} (i,f,g,o).
// Whh slice (64 rows x 512) pinned in LDS (XOR-8 chunk swizzle, conflict-free reads).
// Cell state in registers. Cross-WG step barrier: device-scope atomic counter.
__global__ __launch_bounds__(128) void k_lstm(
    const unsigned short* __restrict__ xwF,   // [S*B, 2048] bf16 (x@Wih^T + biases)
    const unsigned short* __restrict__ xwB,
    const unsigned short* __restrict__ whF,   // [2048, 512] bf16
    const unsigned short* __restrict__ whB,
    unsigned short* __restrict__ hout,        // [S*B, 1024] bf16 (fwd cols 0..511, bwd 512..1023)
    unsigned int* __restrict__ ctrs)          // 2 counters (zeroed)
{
  const int wg = blockIdx.x;
  const int dir = wg >> 5;
  const int ws = wg & 31;
  const int j0 = ws * 16;
  const unsigned short* xw = dir ? xwB : xwF;
  const unsigned short* wh = dir ? whB : whF;
  unsigned int* ctr = ctrs + dir;

  const int tid = threadIdx.x;
  const int wave = tid >> 6;
  const int lane = tid & 63;
  const int lo = lane & 15;
  const int qd = lane >> 4;
  const int mb0 = wave * 16;   // batch base for this wave

  __shared__ unsigned short Ws[64 * 512];   // 64KB

  // preload weight slice: row r (0..63) <- gate row g=(r>>4)*512 + j0 + (r&15)
  for (int p = 0; p < 32; ++p) {
    int c = tid + 128 * p;        // 0..4095 chunks of 8 bf16
    int r = c >> 6;
    int kc = c & 63;
    int g = ((r >> 4) << 9) + j0 + (r & 15);
    int kcs = kc ^ (r & 7);       // XOR swizzle
    *(short8*)&Ws[r * 512 + kcs * 8] = *(const short8*)&wh[(size_t)g * Hx + kc * 8];
  }
  __syncthreads();

  float cst[4] = {0.f, 0.f, 0.f, 0.f};
  const f32x4 zero4 = {0.f, 0.f, 0.f, 0.f};

  for (int s = 0; s < Sx; ++s) {
    int t = dir ? (Sx - 1 - s) : s;
    f32x4 acc4[4] = {zero4, zero4, zero4, zero4};

    if (s > 0) {
      int tprev = dir ? (t + 1) : (t - 1);
      const unsigned short* abase =
          hout + (size_t)tprev * Bx * 1024 + (size_t)(mb0 + lo) * 1024 + dir * Hx + qd * 8;
#pragma unroll 4
      for (int ks = 0; ks < 16; ++ks) {
        short8 af = *(const short8*)(abase + ks * 32);
#pragma unroll
        for (int ni = 0; ni < 4; ++ni) {
          int row = ni * 16 + lo;
          int ch = (ks * 4 + qd) ^ (row & 7);
          short8 bfr = *(const short8*)&Ws[row * 512 + ch * 8];
          acc4[ni] = __builtin_amdgcn_mfma_f32_16x16x32_bf16(af, bfr, acc4[ni], 0, 0, 0);
        }
      }
    }

    const unsigned short* xwt = xw + (size_t)t * Bx * Gx;
#pragma unroll
    for (int r = 0; r < 4; ++r) {
      int b = mb0 + qd * 4 + r;
      const unsigned short* xb = xwt + (size_t)b * Gx + j0 + lo;
      float ip = acc4[0][r] + bf2f(xb[0]);
      float fp = acc4[1][r] + bf2f(xb[512]);
      float gp = acc4[2][r] + bf2f(xb[1024]);
      float op = acc4[3][r] + bf2f(xb[1536]);
      float ct = sigmf(fp) * cst[r] + sigmf(ip) * tanhf(gp);
      cst[r] = ct;
      float hv = sigmf(op) * tanhf(ct);
      hout[((size_t)t * Bx + b) * 1024 + dir * Hx + j0 + lo] = f2bf(hv);
    }

    // step barrier (32 WGs per direction)
    __threadfence();
    __syncthreads();
    if (tid == 0) {
      __hip_atomic_fetch_add(ctr, 1u, __ATOMIC_ACQ_REL, __HIP_MEMORY_SCOPE_AGENT);
      unsigned int tgt = 32u * (unsigned)(s + 1);
      while (__hip_atomic_load(ctr, __ATOMIC_ACQUIRE, __HIP_MEMORY_SCOPE_AGENT) < tgt) {
        __builtin_amdgcn_s_sleep(1);
      }
    }
    __syncthreads();
    __threadfence();
  }
}

// ---------------- FC: logits[row,l] = dot(h1[row,:1024], fc_w[l,:]) + fc_b[l] ----------------
__global__ __launch_bounds__(256) void k_fc(
    const unsigned short* __restrict__ h1,   // [8192,1024] bf16
    const float* __restrict__ fcw,           // [20,1024]
    const float* __restrict__ fcb,           // [20]
    float* __restrict__ logits)              // [8192,20]
{
  int row = blockIdx.x;
  int l = threadIdx.x & 31;
  int sl = threadIdx.x >> 5;   // 0..7
  __shared__ float red[8][32];
  float p = 0.f;
  if (l < Lx) {
    const unsigned short* hr = h1 + (size_t)row * 1024 + sl * 128;
    const float* wr = fcw + l * 1024 + sl * 128;
#pragma unroll 8
    for (int k = 0; k < 128; ++k) p += bf2f(hr[k]) * wr[k];
  }
  red[sl][l] = p;
  __syncthreads();
  if (threadIdx.x < Lx) {
    float s = fcb[threadIdx.x];
#pragma unroll
    for (int i = 0; i < 8; ++i) s += red[i][threadIdx.x];
    logits[(size_t)row * Lx + threadIdx.x] = s;
  }
}

// ---------------- CRF: one block per batch element ----------------
__global__ __launch_bounds__(64) void k_crf(
    const float* __restrict__ logits,   // [(t*32+b)*20 + l]
    const int* __restrict__ labels,     // [B,S]
    const int* __restrict__ mask,       // [B,S]
    const float* __restrict__ trans,    // [20,20]
    const float* __restrict__ startv,
    const float* __restrict__ endv,
    float* __restrict__ out)
{
  int b = blockIdx.x;
  int tid = threadIdx.x;
  __shared__ float tr[Lx * Lx];
  __shared__ float al[2][Lx];
  __shared__ float norm_s;
  for (int i = tid; i < Lx * Lx; i += 64) tr[i] = trans[i];
  if (tid < Lx) al[0][tid] = logits[b * Lx + tid] + startv[tid];
  __syncthreads();
  int cur = 0;
  for (int t = 1; t < Sx; ++t) {
    if (tid < Lx) {
      int to = tid;
      float v[Lx];
      float mx = -1e30f;
#pragma unroll
      for (int f = 0; f < Lx; ++f) { v[f] = al[cur][f] + tr[f * Lx + to]; mx = fmaxf(mx, v[f]); }
      float sum = 0.f;
#pragma unroll
      for (int f = 0; f < Lx; ++f) sum += expf(v[f] - mx);
      float nv = mx + logf(sum) + logits[((size_t)t * Bx + b) * Lx + to];
      int m = mask[b * Sx + t];
      al[1 - cur][to] = (m > 0) ? nv : al[cur][to];
    }
    __syncthreads();
    cur ^= 1;
  }
  if (tid == 0) {
    float mx = -1e30f;
    for (int l = 0; l < Lx; ++l) mx = fmaxf(mx, al[cur][l] + endv[l]);
    float s = 0.f;
    for (int l = 0; l < Lx; ++l) s += expf(al[cur][l] + endv[l] - mx);
    norm_s = mx + logf(s);
  }
  __syncthreads();
  // gold path score (parallel over t, wave reduce)
  const int* lab = labels + b * Sx;
  const int* msk = mask + b * Sx;
  float part = 0.f;
  int msum = 0;
  for (int t = tid; t < Sx; t += 64) {
    int m = msk[t];
    int tg = lab[t];
    if (m > 0) {
      part += logits[((size_t)t * Bx + b) * Lx + tg];
      if (t >= 1) part += tr[lab[t - 1] * Lx + tg];
      msum++;
    }
  }
#pragma unroll
  for (int o = 32; o > 0; o >>= 1) {
    part += __shfl_down(part, o, 64);
    msum += __shfl_down(msum, o, 64);
  }
  if (tid == 0) {
    float gold = part + startv[lab[0]] + endv[lab[msum - 1]];
    atomicAdd(out, (norm_s - gold) * (1.0f / 32.0f));
  }
}

// ---------------- launch ----------------

extern "C" void kernel_launch(void* const* d_in, const int* in_sizes, int n_in,
                              void* d_out, int out_size, void* d_ws, size_t ws_size,
                              hipStream_t stream)
{
  const float* x      = (const float*)d_in[0];
  const int* labels   = (const int*)d_in[1];
  const int* mask     = (const int*)d_in[2];
  const float* wih0f  = (const float*)d_in[3];
  const float* whh0f  = (const float*)d_in[4];
  const float* bih0f  = (const float*)d_in[5];
  const float* bhh0f  = (const float*)d_in[6];
  const float* wih0b  = (const float*)d_in[7];
  const float* whh0b  = (const float*)d_in[8];
  const float* bih0b  = (const float*)d_in[9];
  const float* bhh0b  = (const float*)d_in[10];
  const float* wih1f  = (const float*)d_in[11];
  const float* whh1f  = (const float*)d_in[12];
  const float* bih1f  = (const float*)d_in[13];
  const float* bhh1f  = (const float*)d_in[14];
  const float* wih1b  = (const float*)d_in[15];
  const float* whh1b  = (const float*)d_in[16];
  const float* bih1b  = (const float*)d_in[17];
  const float* bhh1b  = (const float*)d_in[18];
  const float* fcw    = (const float*)d_in[19];
  const float* fcb    = (const float*)d_in[20];
  const float* transm = (const float*)d_in[21];
  const float* startv = (const float*)d_in[22];
  const float* endv   = (const float*)d_in[23];

  char* p = (char*)d_ws;
  auto alloc = [&](size_t bytes) -> char* {
    char* r = p;
    p += (bytes + 255) & ~((size_t)255);
    return r;
  };

  unsigned short* x_bf    = (unsigned short*)alloc((size_t)Rx * Hx * 2);
  unsigned short* wih0f_b = (unsigned short*)alloc((size_t)Gx * Hx * 2);
  unsigned short* wih0b_b = (unsigned short*)alloc((size_t)Gx * Hx * 2);
  unsigned short* whh0f_b = (unsigned short*)alloc((size_t)Gx * Hx * 2);
  unsigned short* whh0b_b = (unsigned short*)alloc((size_t)Gx * Hx * 2);
  unsigned short* wih1f_b = (unsigned short*)alloc((size_t)Gx * 1024 * 2);
  unsigned short* wih1b_b = (unsigned short*)alloc((size_t)Gx * 1024 * 2);
  unsigned short* whh1f_b = (unsigned short*)alloc((size_t)Gx * Hx * 2);
  unsigned short* whh1b_b = (unsigned short*)alloc((size_t)Gx * Hx * 2);
  float* bias0f = (float*)alloc(Gx * 4);
  float* bias0b = (float*)alloc(Gx * 4);
  float* bias1f = (float*)alloc(Gx * 4);
  float* bias1b = (float*)alloc(Gx * 4);
  unsigned short* xw_f = (unsigned short*)alloc((size_t)Rx * Gx * 2);  // reused for layer 1
  unsigned short* xw_b = (unsigned short*)alloc((size_t)Rx * Gx * 2);
  unsigned short* h0   = (unsigned short*)alloc((size_t)Rx * 1024 * 2);
  unsigned short* h1   = (unsigned short*)alloc((size_t)Rx * 1024 * 2);
  float* logits = (float*)alloc((size_t)Rx * Lx * 4);
  unsigned int* ctrs = (unsigned int*)alloc(256);

  if ((size_t)(p - (char*)d_ws) > ws_size) return;  // workspace too small: clean fail

  hipMemsetAsync(ctrs, 0, 256, stream);

  // pack & cast
  k_pack_x<<<(Rx * Hx) / 256, 256, 0, stream>>>(x, x_bf);
  k_cast<<<(Gx * Hx) / 256, 256, 0, stream>>>(wih0f, wih0f_b, Gx * Hx);
  k_cast<<<(Gx * Hx) / 256, 256, 0, stream>>>(wih0b, wih0b_b, Gx * Hx);
  k_cast<<<(Gx * Hx) / 256, 256, 0, stream>>>(whh0f, whh0f_b, Gx * Hx);
  k_cast<<<(Gx * Hx) / 256, 256, 0, stream>>>(whh0b, whh0b_b, Gx * Hx);
  k_cast<<<(Gx * 1024) / 256, 256, 0, stream>>>(wih1f, wih1f_b, Gx * 1024);
  k_cast<<<(Gx * 1024) / 256, 256, 0, stream>>>(wih1b, wih1b_b, Gx * 1024);
  k_cast<<<(Gx * Hx) / 256, 256, 0, stream>>>(whh1f, whh1f_b, Gx * Hx);
  k_cast<<<(Gx * Hx) / 256, 256, 0, stream>>>(whh1b, whh1b_b, Gx * Hx);
  k_add2<<<Gx / 256, 256, 0, stream>>>(bih0f, bhh0f, bias0f, Gx);
  k_add2<<<Gx / 256, 256, 0, stream>>>(bih0b, bhh0b, bias0b, Gx);
  k_add2<<<Gx / 256, 256, 0, stream>>>(bih1f, bhh1f, bias1f, Gx);
  k_add2<<<Gx / 256, 256, 0, stream>>>(bih1b, bhh1b, bias1b, Gx);

  // layer 0: input projections + recurrence
  k_gemm<<<dim3(Gx / 128, Rx / 128), 256, 0, stream>>>(x_bf, wih0f_b, bias0f, xw_f, Rx, Gx, Hx);
  k_gemm<<<dim3(Gx / 128, Rx / 128), 256, 0, stream>>>(x_bf, wih0b_b, bias0b, xw_b, Rx, Gx, Hx);
  k_lstm<<<64, 128, 0, stream>>>(xw_f, xw_b, whh0f_b, whh0b_b, h0, ctrs);

  // layer 1: input projections (K=1024) + recurrence
  k_gemm<<<dim3(Gx / 128, Rx / 128), 256, 0, stream>>>(h0, wih1f_b, bias1f, xw_f, Rx, Gx, 1024);
  k_gemm<<<dim3(Gx / 128, Rx / 128), 256, 0, stream>>>(h0, wih1b_b, bias1b, xw_b, Rx, Gx, 1024);
  k_lstm<<<64, 128, 0, stream>>>(xw_f, xw_b, whh1f_b, whh1b_b, h1, ctrs + 2);

  // FC + CRF
  k_fc<<<Rx, 256, 0, stream>>>(h1, fcw, fcb, logits);
  hipMemsetAsync(d_out, 0, 4, stream);
  k_crf<<<Bx, 64, 0, stream>>>(logits, labels, mask, transm, startv, endv, (float*)d_out);
}

// Round 2
// 4635.349 us; speedup vs baseline: 1.3767x; 1.3767x over previous
//
#include <hip/hip_runtime.h>

// Problem constants
#define Sx 256
#define Bx 32
#define Hx 512
#define Gx 2048   // 4H
#define Lx 20
#define Rx 8192   // S*B

typedef __attribute__((ext_vector_type(8))) short short8;
typedef __attribute__((ext_vector_type(4))) float f32x4;
typedef __attribute__((ext_vector_type(16))) float f32x16;

__device__ __forceinline__ unsigned short f2bf(float f) {
  union { float f; unsigned u; } v; v.f = f;
  unsigned u = v.u;
  return (unsigned short)((u + 0x7fffu + ((u >> 16) & 1u)) >> 16);
}
__device__ __forceinline__ float bf2f(unsigned short h) {
  union { unsigned u; float f; } v; v.u = ((unsigned)h) << 16;
  return v.f;
}
__device__ __forceinline__ float bfh(unsigned long long x, int r) {
  return bf2f((unsigned short)((x >> (16 * r)) & 0xffffull));
}
__device__ __forceinline__ float sigmf(float x) { return 1.0f / (1.0f + expf(-x)); }

// ---------------- pack / cast kernels ----------------

// x: [B,S,H] fp32 -> xbf: [S,B,H] bf16 (transpose + cast)
__global__ void k_pack_x(const float* __restrict__ x, unsigned short* __restrict__ xbf) {
  int tid = blockIdx.x * 256 + threadIdx.x;      // 0 .. S*B*H-1
  int h = tid & (Hx - 1);
  int r = tid >> 9;          // t*32+b
  int b = r & 31;
  int t = r >> 5;
  xbf[tid] = f2bf(x[(b * Sx + t) * Hx + h]);
}

__global__ void k_cast(const float* __restrict__ s, unsigned short* __restrict__ d, int n) {
  int i = blockIdx.x * 256 + threadIdx.x;
  if (i < n) d[i] = f2bf(s[i]);
}

__global__ void k_add2(const float* __restrict__ a, const float* __restrict__ b,
                       float* __restrict__ o, int n) {
  int i = blockIdx.x * 256 + threadIdx.x;
  if (i < n) o[i] = a[i] + b[i];
}

// ---------------- GEMM: C[M,N](bf16) = A[M,K](bf16) * Bw[N,K]^T(bf16) + bias[N] ----------------
__global__ __launch_bounds__(256) void k_gemm(
    const unsigned short* __restrict__ A,
    const unsigned short* __restrict__ Bw,
    const float* __restrict__ bias,
    unsigned short* __restrict__ C,
    int M, int N, int K)
{
  const int bn = blockIdx.x, bm = blockIdx.y;
  const int tid = threadIdx.x;
  const int w = tid >> 6, lane = tid & 63;
  const int wr = w >> 1, wc = w & 1;
  const int lo = lane & 15, qd = lane >> 4;

  __shared__ unsigned short As[128 * 72];
  __shared__ unsigned short Bs[128 * 72];

  f32x4 acc[4][4] = {};

  const int ktn = K >> 6;
  for (int kt = 0; kt < ktn; ++kt) {
    __syncthreads();
#pragma unroll
    for (int p = 0; p < 4; ++p) {
      int c = tid + (p << 8);
      int row = c >> 3, kc = c & 7;
      *(short8*)&As[row * 72 + kc * 8] =
          *(const short8*)&A[(size_t)(bm * 128 + row) * K + kt * 64 + kc * 8];
      *(short8*)&Bs[row * 72 + kc * 8] =
          *(const short8*)&Bw[(size_t)(bn * 128 + row) * K + kt * 64 + kc * 8];
    }
    __syncthreads();
#pragma unroll
    for (int kk = 0; kk < 2; ++kk) {
      short8 af[4], bfr[4];
#pragma unroll
      for (int mi = 0; mi < 4; ++mi)
        af[mi] = *(const short8*)&As[(wr * 64 + mi * 16 + lo) * 72 + kk * 32 + qd * 8];
#pragma unroll
      for (int ni = 0; ni < 4; ++ni)
        bfr[ni] = *(const short8*)&Bs[(wc * 64 + ni * 16 + lo) * 72 + kk * 32 + qd * 8];
#pragma unroll
      for (int mi = 0; mi < 4; ++mi)
#pragma unroll
        for (int ni = 0; ni < 4; ++ni)
          acc[mi][ni] = __builtin_amdgcn_mfma_f32_16x16x32_bf16(af[mi], bfr[ni], acc[mi][ni], 0, 0, 0);
    }
  }
#pragma unroll
  for (int mi = 0; mi < 4; ++mi) {
#pragma unroll
    for (int ni = 0; ni < 4; ++ni) {
      int n = bn * 128 + wc * 64 + ni * 16 + lo;
      float bv = bias[n];
#pragma unroll
      for (int r = 0; r < 4; ++r) {
        int m = bm * 128 + wr * 64 + mi * 16 + qd * 4 + r;
        C[(size_t)m * N + n] = f2bf(acc[mi][ni][r] + bv);
      }
    }
  }
}

// ---------------- persistent bidirectional LSTM recurrence (v2) ----------------
// 64 WGs x 64 threads. dir = wg>>5, slice ws = wg&31 owns j in [ws*16, ws*16+16).
// One wave per WG: MFMA 32x32x16, C = W_slice[64 gate-rows] x h_prev^T[32 batches].
// Lane (bn=lane&31, q=lane>>5) owns batch bn, j-locals {q*4+r, 8+q*4+r}.
// h handoff: packed u64 write-through (sc1) stores + release counter; readers
// relaxed-poll + one acquire fence (buffer_inv) then plain vector loads.
__global__ __launch_bounds__(64) void k_lstm(
    const unsigned short* __restrict__ xwF,   // [S*B, 2048] bf16 (x@Wih^T + biases)
    const unsigned short* __restrict__ xwB,
    const unsigned short* __restrict__ whF,   // [2048, 512] bf16
    const unsigned short* __restrict__ whB,
    unsigned short* __restrict__ hout,        // [S*B, 1024] bf16 (fwd 0..511, bwd 512..1023)
    unsigned int* __restrict__ ctrs)          // ctrs[0]=dir0, ctrs[64]=dir1 (zeroed)
{
  const int wg = blockIdx.x;
  const int dir = wg >> 5;
  const int ws = wg & 31;
  const int j0 = ws * 16;
  const unsigned short* xw = dir ? xwB : xwF;
  const unsigned short* wh = dir ? whB : whF;
  unsigned int* ctr = ctrs + dir * 64;

  const int lane = threadIdx.x;   // 0..63
  const int bn = lane & 31;       // batch (MFMA n / A row m)
  const int q  = lane >> 5;       // 0/1

  __shared__ unsigned short Ws[64 * 512];   // 64KB, XOR-swizzled chunks

  // preload: LDS row rr = c*16 + jl  <-  W row g = c*512 + j0 + jl
  for (int rr = 0; rr < 64; ++rr) {
    int g = ((rr >> 4) << 9) + j0 + (rr & 15);
    int pc = lane ^ (rr & 7);     // store logical chunk `lane` at swizzled pos
    *(short8*)&Ws[rr * 512 + pc * 8] = *(const short8*)&wh[(size_t)g * Hx + lane * 8];
  }
  __syncthreads();

  float cst[2][4] = {};

  for (int s = 0; s < Sx; ++s) {
    const int t = dir ? (Sx - 1 - s) : s;

    // prefetch xw for this lane (independent of h_prev; issue before the poll)
    const unsigned short* xwt = xw + ((size_t)t * Bx + bn) * Gx + j0 + q * 4;
    unsigned long long xg[4][2];
#pragma unroll
    for (int c = 0; c < 4; ++c)
#pragma unroll
      for (int jg = 0; jg < 2; ++jg)
        xg[c][jg] = *(const unsigned long long*)(xwt + c * 512 + jg * 8);

    f32x16 acc0 = {};
    f32x16 acc1 = {};

    if (s > 0) {
      const unsigned tgt = 32u * (unsigned)s;
      while (__hip_atomic_load(ctr, __ATOMIC_RELAXED, __HIP_MEMORY_SCOPE_AGENT) < tgt)
        __builtin_amdgcn_s_sleep(1);
      __builtin_amdgcn_fence(__ATOMIC_ACQUIRE, "agent");

      const int tp = dir ? (t + 1) : (t - 1);
      const unsigned short* hb = hout + ((size_t)tp * Bx + bn) * 1024 + dir * Hx + q * 8;
#pragma unroll
      for (int ks = 0; ks < 32; ++ks) {
        // B-frag: h_prev[batch=bn][k = ks*16 + q*8 .. +8]
        short8 bfr = *(const short8*)(hb + ks * 16);
        int lc = ks * 2 + q;                       // logical 8-elem chunk
        int pc = lc ^ (bn & 7);                    // swizzled
        short8 af0 = *(const short8*)&Ws[bn * 512 + pc * 8];          // tile0: rows 0..31
        short8 af1 = *(const short8*)&Ws[(32 + bn) * 512 + pc * 8];   // tile1: rows 32..63
        acc0 = __builtin_amdgcn_mfma_f32_32x32x16_bf16(af0, bfr, acc0, 0, 0, 0);
        acc1 = __builtin_amdgcn_mfma_f32_32x32x16_bf16(af1, bfr, acc1, 0, 0, 0);
      }
    }

    // epilogue: lane computes h for batch bn, j = j0 + jg*8 + q*4 + r
    unsigned short* hw = hout + ((size_t)t * Bx + bn) * 1024 + dir * Hx + j0;
#pragma unroll
    for (int jg = 0; jg < 2; ++jg) {
      unsigned long long hv = 0;
#pragma unroll
      for (int r = 0; r < 4; ++r) {
        float iv = acc0[jg * 4 + r]     + bfh(xg[0][jg], r);
        float fv = acc0[8 + jg * 4 + r] + bfh(xg[1][jg], r);
        float gv = acc1[jg * 4 + r]     + bfh(xg[2][jg], r);
        float ov = acc1[8 + jg * 4 + r] + bfh(xg[3][jg], r);
        float ct = sigmf(fv) * cst[jg][r] + sigmf(iv) * tanhf(gv);
        cst[jg][r] = ct;
        float hvf = sigmf(ov) * tanhf(ct);
        hv |= (unsigned long long)f2bf(hvf) << (16 * r);
      }
      // write-through to coherence point (visible device-wide, no L2 writeback)
      __hip_atomic_store((unsigned long long*)(hw + jg * 8 + q * 4), hv,
                         __ATOMIC_RELAXED, __HIP_MEMORY_SCOPE_AGENT);
    }

    // publish: release orders this wave's sc1 stores (vmcnt drain) before the add
    if (lane == 0)
      __hip_atomic_fetch_add(ctr, 1u, __ATOMIC_RELEASE, __HIP_MEMORY_SCOPE_AGENT);
  }
}

// ---------------- FC ----------------
__global__ __launch_bounds__(256) void k_fc(
    const unsigned short* __restrict__ h1,   // [8192,1024] bf16
    const float* __restrict__ fcw,           // [20,1024]
    const float* __restrict__ fcb,           // [20]
    float* __restrict__ logits)              // [8192,20]
{
  int row = blockIdx.x;
  int l = threadIdx.x & 31;
  int sl = threadIdx.x >> 5;   // 0..7
  __shared__ float red[8][32];
  float p = 0.f;
  if (l < Lx) {
    const unsigned short* hr = h1 + (size_t)row * 1024 + sl * 128;
    const float* wr = fcw + l * 1024 + sl * 128;
#pragma unroll 8
    for (int k = 0; k < 128; ++k) p += bf2f(hr[k]) * wr[k];
  }
  red[sl][l] = p;
  __syncthreads();
  if (threadIdx.x < Lx) {
    float s = fcb[threadIdx.x];
#pragma unroll
    for (int i = 0; i < 8; ++i) s += red[i][threadIdx.x];
    logits[(size_t)row * Lx + threadIdx.x] = s;
  }
}

// ---------------- CRF ----------------
__global__ __launch_bounds__(64) void k_crf(
    const float* __restrict__ logits,   // [(t*32+b)*20 + l]
    const int* __restrict__ labels,     // [B,S]
    const int* __restrict__ mask,       // [B,S]
    const float* __restrict__ trans,    // [20,20]
    const float* __restrict__ startv,
    const float* __restrict__ endv,
    float* __restrict__ out)
{
  int b = blockIdx.x;
  int tid = threadIdx.x;
  __shared__ float tr[Lx * Lx];
  __shared__ float al[2][Lx];
  __shared__ float norm_s;
  for (int i = tid; i < Lx * Lx; i += 64) tr[i] = trans[i];
  if (tid < Lx) al[0][tid] = logits[b * Lx + tid] + startv[tid];
  __syncthreads();
  int cur = 0;
  for (int t = 1; t < Sx; ++t) {
    if (tid < Lx) {
      int to = tid;
      float v[Lx];
      float mx = -1e30f;
#pragma unroll
      for (int f = 0; f < Lx; ++f) { v[f] = al[cur][f] + tr[f * Lx + to]; mx = fmaxf(mx, v[f]); }
      float sum = 0.f;
#pragma unroll
      for (int f = 0; f < Lx; ++f) sum += expf(v[f] - mx);
      float nv = mx + logf(sum) + logits[((size_t)t * Bx + b) * Lx + to];
      int m = mask[b * Sx + t];
      al[1 - cur][to] = (m > 0) ? nv : al[cur][to];
    }
    __syncthreads();
    cur ^= 1;
  }
  if (tid == 0) {
    float mx = -1e30f;
    for (int l = 0; l < Lx; ++l) mx = fmaxf(mx, al[cur][l] + endv[l]);
    float s = 0.f;
    for (int l = 0; l < Lx; ++l) s += expf(al[cur][l] + endv[l] - mx);
    norm_s = mx + logf(s);
  }
  __syncthreads();
  const int* lab = labels + b * Sx;
  const int* msk = mask + b * Sx;
  float part = 0.f;
  int msum = 0;
  for (int t = tid; t < Sx; t += 64) {
    int m = msk[t];
    int tg = lab[t];
    if (m > 0) {
      part += logits[((size_t)t * Bx + b) * Lx + tg];
      if (t >= 1) part += tr[lab[t - 1] * Lx + tg];
      msum++;
    }
  }
#pragma unroll
  for (int o = 32; o > 0; o >>= 1) {
    part += __shfl_down(part, o, 64);
    msum += __shfl_down(msum, o, 64);
  }
  if (tid == 0) {
    float gold = part + startv[lab[0]] + endv[lab[msum - 1]];
    atomicAdd(out, (norm_s - gold) * (1.0f / 32.0f));
  }
}

// ---------------- launch ----------------

extern "C" void kernel_launch(void* const* d_in, const int* in_sizes, int n_in,
                              void* d_out, int out_size, void* d_ws, size_t ws_size,
                              hipStream_t stream)
{
  const float* x      = (const float*)d_in[0];
  const int* labels   = (const int*)d_in[1];
  const int* mask     = (const int*)d_in[2];
  const float* wih0f  = (const float*)d_in[3];
  const float* whh0f  = (const float*)d_in[4];
  const float* bih0f  = (const float*)d_in[5];
  const float* bhh0f  = (const float*)d_in[6];
  const float* wih0b  = (const float*)d_in[7];
  const float* whh0b  = (const float*)d_in[8];
  const float* bih0b  = (const float*)d_in[9];
  const float* bhh0b  = (const float*)d_in[10];
  const float* wih1f  = (const float*)d_in[11];
  const float* whh1f  = (const float*)d_in[12];
  const float* bih1f  = (const float*)d_in[13];
  const float* bhh1f  = (const float*)d_in[14];
  const float* wih1b  = (const float*)d_in[15];
  const float* whh1b  = (const float*)d_in[16];
  const float* bih1b  = (const float*)d_in[17];
  const float* bhh1b  = (const float*)d_in[18];
  const float* fcw    = (const float*)d_in[19];
  const float* fcb    = (const float*)d_in[20];
  const float* transm = (const float*)d_in[21];
  const float* startv = (const float*)d_in[22];
  const float* endv   = (const float*)d_in[23];

  char* p = (char*)d_ws;
  auto alloc = [&](size_t bytes) -> char* {
    char* r = p;
    p += (bytes + 255) & ~((size_t)255);
    return r;
  };

  unsigned short* x_bf    = (unsigned short*)alloc((size_t)Rx * Hx * 2);
  unsigned short* wih0f_b = (unsigned short*)alloc((size_t)Gx * Hx * 2);
  unsigned short* wih0b_b = (unsigned short*)alloc((size_t)Gx * Hx * 2);
  unsigned short* whh0f_b = (unsigned short*)alloc((size_t)Gx * Hx * 2);
  unsigned short* whh0b_b = (unsigned short*)alloc((size_t)Gx * Hx * 2);
  unsigned short* wih1f_b = (unsigned short*)alloc((size_t)Gx * 1024 * 2);
  unsigned short* wih1b_b = (unsigned short*)alloc((size_t)Gx * 1024 * 2);
  unsigned short* whh1f_b = (unsigned short*)alloc((size_t)Gx * Hx * 2);
  unsigned short* whh1b_b = (unsigned short*)alloc((size_t)Gx * Hx * 2);
  float* bias0f = (float*)alloc(Gx * 4);
  float* bias0b = (float*)alloc(Gx * 4);
  float* bias1f = (float*)alloc(Gx * 4);
  float* bias1b = (float*)alloc(Gx * 4);
  unsigned short* xw_f = (unsigned short*)alloc((size_t)Rx * Gx * 2);
  unsigned short* xw_b = (unsigned short*)alloc((size_t)Rx * Gx * 2);
  unsigned short* h0   = (unsigned short*)alloc((size_t)Rx * 1024 * 2);
  unsigned short* h1   = (unsigned short*)alloc((size_t)Rx * 1024 * 2);
  float* logits = (float*)alloc((size_t)Rx * Lx * 4);
  unsigned int* ctrs = (unsigned int*)alloc(1024);

  if ((size_t)(p - (char*)d_ws) > ws_size) return;

  hipMemsetAsync(ctrs, 0, 1024, stream);

  // pack & cast
  k_pack_x<<<(Rx * Hx) / 256, 256, 0, stream>>>(x, x_bf);
  k_cast<<<(Gx * Hx) / 256, 256, 0, stream>>>(wih0f, wih0f_b, Gx * Hx);
  k_cast<<<(Gx * Hx) / 256, 256, 0, stream>>>(wih0b, wih0b_b, Gx * Hx);
  k_cast<<<(Gx * Hx) / 256, 256, 0, stream>>>(whh0f, whh0f_b, Gx * Hx);
  k_cast<<<(Gx * Hx) / 256, 256, 0, stream>>>(whh0b, whh0b_b, Gx * Hx);
  k_cast<<<(Gx * 1024) / 256, 256, 0, stream>>>(wih1f, wih1f_b, Gx * 1024);
  k_cast<<<(Gx * 1024) / 256, 256, 0, stream>>>(wih1b, wih1b_b, Gx * 1024);
  k_cast<<<(Gx * Hx) / 256, 256, 0, stream>>>(whh1f, whh1f_b, Gx * Hx);
  k_cast<<<(Gx * Hx) / 256, 256, 0, stream>>>(whh1b, whh1b_b, Gx * Hx);
  k_add2<<<Gx / 256, 256, 0, stream>>>(bih0f, bhh0f, bias0f, Gx);
  k_add2<<<Gx / 256, 256, 0, stream>>>(bih0b, bhh0b, bias0b, Gx);
  k_add2<<<Gx / 256, 256, 0, stream>>>(bih1f, bhh1f, bias1f, Gx);
  k_add2<<<Gx / 256, 256, 0, stream>>>(bih1b, bhh1b, bias1b, Gx);

  // layer 0
  k_gemm<<<dim3(Gx / 128, Rx / 128), 256, 0, stream>>>(x_bf, wih0f_b, bias0f, xw_f, Rx, Gx, Hx);
  k_gemm<<<dim3(Gx / 128, Rx / 128), 256, 0, stream>>>(x_bf, wih0b_b, bias0b, xw_b, Rx, Gx, Hx);
  k_lstm<<<64, 64, 0, stream>>>(xw_f, xw_b, whh0f_b, whh0b_b, h0, ctrs);

  // layer 1
  k_gemm<<<dim3(Gx / 128, Rx / 128), 256, 0, stream>>>(h0, wih1f_b, bias1f, xw_f, Rx, Gx, 1024);
  k_gemm<<<dim3(Gx / 128, Rx / 128), 256, 0, stream>>>(h0, wih1b_b, bias1b, xw_b, Rx, Gx, 1024);
  k_lstm<<<64, 64, 0, stream>>>(xw_f, xw_b, whh1f_b, whh1b_b, h1, ctrs + 128);

  // FC + CRF
  k_fc<<<Rx, 256, 0, stream>>>(h1, fcw, fcb, logits);
  hipMemsetAsync(d_out, 0, 4, stream);
  k_crf<<<Bx, 64, 0, stream>>>(logits, labels, mask, transm, startv, endv, (float*)d_out);
}